// Round 1
// baseline (311.768 us; speedup 1.0000x reference)
//
#include <hip/hip_runtime.h>

typedef float          vfloat4  __attribute__((ext_vector_type(4)));
typedef int            vint4    __attribute__((ext_vector_type(4)));

#define BSHIFT 12
#define BSIZE  4096      // DOFs per bucket (16 KB LDS accumulator)
#define G1     512       // workgroups for chunked passes
#define TPBC   1024      // 16 waves/WG -> full wave-slot occupancy
#define TPB    256

// u1[bc[k]] = w1[k] * u[bc[k]]
__global__ void scatter_u1_kernel(const float* __restrict__ u,
                                  const float* __restrict__ w1,
                                  const int* __restrict__ bc,
                                  float* __restrict__ u1, int n) {
    int k = blockIdx.x * blockDim.x + threadIdx.x;
    if (k < n) {
        int idx = bc[k];
        u1[idx] = w1[k] * u[idx];
    }
}

// Pass 1 (cheap, stream-only): per-WG bucket histogram of edof.
// 16 MB edof stream + LDS atomics; no scattered global traffic.
// Chunking MUST match compute_scatter_kernel so cnt[b][wg] lines up.
__global__ void hist_kernel(const int* __restrict__ edof,
                            int* __restrict__ cnt,   // [nb][G1]
                            int total, int nb, int chunk) {
    __shared__ int h[256];
    int wg = blockIdx.x;
    if (threadIdx.x < nb) h[threadIdx.x] = 0;
    __syncthreads();
    int k0 = wg * chunk;
    int k1 = min(k0 + chunk, total);
    // chunk is a multiple of TPBC*4 and total%4==0, so no partial tail.
    for (int k = k0 + threadIdx.x * 4; k + 4 <= k1; k += TPBC * 4) {
        vint4 idx = __builtin_nontemporal_load((const vint4*)(edof + k));
        atomicAdd(&h[idx.x >> BSHIFT], 1);
        atomicAdd(&h[idx.y >> BSHIFT], 1);
        atomicAdd(&h[idx.z >> BSHIFT], 1);
        atomicAdd(&h[idx.w >> BSHIFT], 1);
    }
    __syncthreads();
    if (threadIdx.x < nb) cnt[threadIdx.x * G1 + wg] = h[threadIdx.x];
}

// Per-bucket exclusive scan over the G1 workgroup counts. 1 wave/bucket.
__global__ void scan_bucket_kernel(const int* __restrict__ cnt,  // [nb][G1]
                                   int* __restrict__ wgoff,      // [nb][G1]
                                   int* __restrict__ btot) {     // [nb]
    int b = blockIdx.x;
    int lane = threadIdx.x;          // 0..63
    const int per = G1 / 64;
    int v[per];
    int s = 0;
    for (int j = 0; j < per; ++j) { v[j] = cnt[b * G1 + lane * per + j]; s += v[j]; }
    int incl = s;
    for (int off = 1; off < 64; off <<= 1) {
        int n = __shfl_up(incl, off, 64);
        if (lane >= off) incl += n;
    }
    int run = incl - s;
    for (int j = 0; j < per; ++j) { wgoff[b * G1 + lane * per + j] = run; run += v[j]; }
    if (lane == 63) btot[b] = incl;
}

// Wave-parallel exclusive scan of bucket totals (nb <= 256).
__global__ void scan_total_kernel(const int* __restrict__ btot,
                                  int* __restrict__ bstart, int nb) {
    int lane = threadIdx.x;          // 64 threads
    int v[4];
    int s = 0;
    for (int j = 0; j < 4; ++j) {
        int i = lane * 4 + j;
        v[j] = (i < nb) ? btot[i] : 0;
        s += v[j];
    }
    int incl = s;
    for (int off = 1; off < 64; off <<= 1) {
        int n = __shfl_up(incl, off, 64);
        if (lane >= off) incl += n;
    }
    int run = incl - s;
    for (int j = 0; j < 4; ++j) {
        int i = lane * 4 + j;
        if (i < nb) bstart[i] = run;
        run += v[j];
    }
    if (lane == 63) bstart[nb] = incl;   // grand total
}

// Pass 2 (fused heavy pass): 8 threads/element, fe_i = sum_j K[i][j]*ue_j,
// then DIRECT rank-scatter of the packed 4B entry into bucket-sorted order.
// entry = (idx_within_bucket << 16) | fp16(fe). Only LDS atomics for ranks.
// The u1 gather (read) and the pairs scatter (write) now overlap inside one
// pass instead of paying two serialized scatter-limited passes, and fe never
// round-trips through HBM (febuf16 eliminated).
__global__ void compute_scatter_kernel(const float* __restrict__ u1,
                                       const int* __restrict__ edof,
                                       const float* __restrict__ stiff,
                                       const int* __restrict__ wgoff, // [nb][G1]
                                       const int* __restrict__ bstart,
                                       unsigned int* __restrict__ pairs,
                                       int total, int nb, int chunk) {
    __shared__ int base[256];
    int wg = blockIdx.x;
    if (threadIdx.x < nb)
        base[threadIdx.x] = bstart[threadIdx.x] + wgoff[threadIdx.x * G1 + wg];
    __syncthreads();
    int k0 = wg * chunk;
    int k1 = min(k0 + chunk, total);
    for (int k = k0 + threadIdx.x; k < k1; k += TPBC) {
        int e = k >> 3;
        int i = k & 7;
        int idx = __builtin_nontemporal_load(edof + k);
        float ue = u1[idx];

        const vfloat4* Kr = (const vfloat4*)(stiff + (size_t)e * 64 + (size_t)i * 8);
        vfloat4 ka = __builtin_nontemporal_load(Kr);
        vfloat4 kb = __builtin_nontemporal_load(Kr + 1);

        float fe;
        fe  = ka.x * __shfl(ue, 0, 8);
        fe += ka.y * __shfl(ue, 1, 8);
        fe += ka.z * __shfl(ue, 2, 8);
        fe += ka.w * __shfl(ue, 3, 8);
        fe += kb.x * __shfl(ue, 4, 8);
        fe += kb.y * __shfl(ue, 5, 8);
        fe += kb.z * __shfl(ue, 6, 8);
        fe += kb.w * __shfl(ue, 7, 8);

        unsigned short hu = __builtin_bit_cast(unsigned short, (_Float16)fe);
        int b = idx >> BSHIFT;
        int pos = atomicAdd(&base[b], 1);
        pairs[pos] = ((unsigned)(idx & (BSIZE - 1)) << 16) | (unsigned)hu;
    }
}

// One workgroup per bucket. LDS fp32 accumulate, coalesced store.
// 1024 threads (was 512): only nb (~245) WGs exist, so deepen per-WG
// parallelism to hide the pairs-read + LDS-atomic latency.
// Covers every DOF, so no F memset needed.
__global__ void bucket_reduce_kernel(const unsigned int* __restrict__ pairs,
                                     const int* __restrict__ bstart,
                                     float* __restrict__ F, int ndof) {
    __shared__ float acc[BSIZE];
    int b = blockIdx.x;
    for (int j = threadIdx.x; j < BSIZE; j += 1024) acc[j] = 0.0f;
    __syncthreads();
    int k0 = bstart[b], k1 = bstart[b + 1];
    for (int k = k0 + threadIdx.x; k < k1; k += 1024) {
        unsigned p = pairs[k];
        float fe = (float)__builtin_bit_cast(_Float16, (unsigned short)(p & 0xffffu));
        atomicAdd(&acc[p >> 16], fe);
    }
    __syncthreads();
    int gbase = b << BSHIFT;
    for (int j = threadIdx.x; j < BSIZE; j += 1024) {
        int g = gbase + j;
        if (g < ndof) F[g] = acc[j];
    }
}

// Fallback (fused atomics) if ws too small.
__global__ void elem_assemble_kernel(const float* __restrict__ u1,
                                     const int* __restrict__ edof,
                                     const float* __restrict__ stiff,
                                     float* __restrict__ F, int nelem) {
    int t = blockIdx.x * blockDim.x + threadIdx.x;
    int e = t >> 3;
    if (e >= nelem) return;
    int i = t & 7;
    int idx = __builtin_nontemporal_load(edof + t);
    float ue = u1[idx];
    const vfloat4* Kr = (const vfloat4*)(stiff + (size_t)e * 64 + (size_t)i * 8);
    vfloat4 k0 = __builtin_nontemporal_load(Kr);
    vfloat4 k1 = __builtin_nontemporal_load(Kr + 1);
    float fe;
    fe  = k0.x * __shfl(ue, 0, 8);
    fe += k0.y * __shfl(ue, 1, 8);
    fe += k0.z * __shfl(ue, 2, 8);
    fe += k0.w * __shfl(ue, 3, 8);
    fe += k1.x * __shfl(ue, 4, 8);
    fe += k1.y * __shfl(ue, 5, 8);
    fe += k1.z * __shfl(ue, 6, 8);
    fe += k1.w * __shfl(ue, 7, 8);
    unsafeAtomicAdd(&F[idx], fe);
}

extern "C" void kernel_launch(void* const* d_in, const int* in_sizes, int n_in,
                              void* d_out, int out_size, void* d_ws, size_t ws_size,
                              hipStream_t stream) {
    const float* u     = (const float*)d_in[0];
    const float* w1    = (const float*)d_in[1];
    const int*   bc    = (const int*)d_in[2];
    const int*   edof  = (const int*)d_in[3];
    const float* stiff = (const float*)d_in[4];
    float* F = (float*)d_out;

    int ndof  = in_sizes[0];
    int nbc   = in_sizes[2];
    int total = in_sizes[3];      // NELEM * 8
    int nelem = total / 8;
    int nb    = (ndof + BSIZE - 1) >> BSHIFT;

    // Carve workspace (256 B aligned chunks).
    char* w = (char*)d_ws;
    size_t o = 0;
    auto take = [&](size_t nbytes) -> char* {
        char* p = w + o;
        o += (nbytes + 255) & ~(size_t)255;
        return p;
    };
    float* u1 = (float*)take((size_t)ndof * 4);
    unsigned int* pairs = (unsigned int*)take((size_t)total * 4);
    int* cnt    = (int*)take((size_t)nb * G1 * 4);
    int* wgoff  = (int*)take((size_t)nb * G1 * 4);
    int* btot   = (int*)take((size_t)nb * 4);
    int* bstart = (int*)take((size_t)(nb + 1) * 4);

    (void)hipMemsetAsync(u1, 0, (size_t)ndof * sizeof(float), stream);
    scatter_u1_kernel<<<(nbc + TPB - 1) / TPB, TPB, 0, stream>>>(u, w1, bc, u1, nbc);

    if (o <= ws_size && nb <= 256 && total % 8 == 0) {
        // chunk: multiple of TPBC*4 (vint4 stride alignment in hist),
        // shared by both chunked kernels so cnt/wgoff line up.
        int chunk = (((total + G1 - 1) / G1) + TPBC * 4 - 1) & ~(TPBC * 4 - 1);
        hist_kernel<<<G1, TPBC, 0, stream>>>(edof, cnt, total, nb, chunk);
        scan_bucket_kernel<<<nb, 64, 0, stream>>>(cnt, wgoff, btot);
        scan_total_kernel<<<1, 64, 0, stream>>>(btot, bstart, nb);
        compute_scatter_kernel<<<G1, TPBC, 0, stream>>>(
            u1, edof, stiff, wgoff, bstart, pairs, total, nb, chunk);
        bucket_reduce_kernel<<<nb, 1024, 0, stream>>>(pairs, bstart, F, ndof);
    } else {
        (void)hipMemsetAsync(F, 0, (size_t)ndof * sizeof(float), stream);
        elem_assemble_kernel<<<(total + TPB - 1) / TPB, TPB, 0, stream>>>(
            u1, edof, stiff, F, nelem);
    }
}

// Round 2
// 280.728 us; speedup vs baseline: 1.1106x; 1.1106x over previous
//
#include <hip/hip_runtime.h>

typedef float          vfloat4  __attribute__((ext_vector_type(4)));
typedef int            vint4    __attribute__((ext_vector_type(4)));

#define BSHIFT 12
#define BSIZE  4096      // DOFs per bucket (16 KB LDS accumulator in reduce)
#define G1     1024      // workgroups for chunked passes
#define TPBC   512       // threads/WG: 8 waves; 4 WGs/CU -> 32 waves/CU
#define RPT    8         // entries per thread per flush batch
#define BATCH  (TPBC * RPT)   // 4096 entries staged per WG-batch
#define CAP    28        // staged slots per bucket per batch (lambda~16.7)
#define TPB    256

// u1[bc[k]] = w1[k] * u[bc[k]]
__global__ void scatter_u1_kernel(const float* __restrict__ u,
                                  const float* __restrict__ w1,
                                  const int* __restrict__ bc,
                                  float* __restrict__ u1, int n) {
    int k = blockIdx.x * blockDim.x + threadIdx.x;
    if (k < n) {
        int idx = bc[k];
        u1[idx] = w1[k] * u[idx];
    }
}

// Pass 1 (cheap, stream-only): per-WG bucket histogram of edof.
// Chunking MUST match compute_scatter_kernel so cnt[b][wg] lines up.
__global__ void hist_kernel(const int* __restrict__ edof,
                            int* __restrict__ cnt,   // [nb][G1]
                            int total, int nb, int chunk) {
    __shared__ int h[256];
    int wg = blockIdx.x;
    if (threadIdx.x < nb) h[threadIdx.x] = 0;
    __syncthreads();
    int k0 = wg * chunk;
    int k1 = min(k0 + chunk, total);
    for (int k = k0 + threadIdx.x * 4; k + 4 <= k1; k += TPBC * 4) {
        vint4 idx = __builtin_nontemporal_load((const vint4*)(edof + k));
        atomicAdd(&h[idx.x >> BSHIFT], 1);
        atomicAdd(&h[idx.y >> BSHIFT], 1);
        atomicAdd(&h[idx.z >> BSHIFT], 1);
        atomicAdd(&h[idx.w >> BSHIFT], 1);
    }
    __syncthreads();
    if (threadIdx.x < nb) cnt[threadIdx.x * G1 + wg] = h[threadIdx.x];
}

// Per-bucket exclusive scan over the G1 workgroup counts. 1 wave/bucket.
__global__ void scan_bucket_kernel(const int* __restrict__ cnt,  // [nb][G1]
                                   int* __restrict__ wgoff,      // [nb][G1]
                                   int* __restrict__ btot) {     // [nb]
    int b = blockIdx.x;
    int lane = threadIdx.x;          // 0..63
    const int per = G1 / 64;
    int v[per];
    int s = 0;
    for (int j = 0; j < per; ++j) { v[j] = cnt[b * G1 + lane * per + j]; s += v[j]; }
    int incl = s;
    for (int off = 1; off < 64; off <<= 1) {
        int n = __shfl_up(incl, off, 64);
        if (lane >= off) incl += n;
    }
    int run = incl - s;
    for (int j = 0; j < per; ++j) { wgoff[b * G1 + lane * per + j] = run; run += v[j]; }
    if (lane == 63) btot[b] = incl;
}

// Wave-parallel exclusive scan of bucket totals (nb <= 256).
__global__ void scan_total_kernel(const int* __restrict__ btot,
                                  int* __restrict__ bstart, int nb) {
    int lane = threadIdx.x;          // 64 threads
    int v[4];
    int s = 0;
    for (int j = 0; j < 4; ++j) {
        int i = lane * 4 + j;
        v[j] = (i < nb) ? btot[i] : 0;
        s += v[j];
    }
    int incl = s;
    for (int off = 1; off < 64; off <<= 1) {
        int n = __shfl_up(incl, off, 64);
        if (lane >= off) incl += n;
    }
    int run = incl - s;
    for (int j = 0; j < 4; ++j) {
        int i = lane * 4 + j;
        if (i < nb) bstart[i] = run;
        run += v[j];
    }
    if (lane == 63) bstart[nb] = incl;   // grand total
}

// Pass 2 (fused heavy pass + software write-combining):
// 8 threads/element compute fe, then stage the packed 4B entry into a
// per-bucket LDS buffer. Every BATCH entries the WG flushes all staged
// entries COALESCED (contiguous runs per bucket) into the reserved
// [bucket][wg] region of `pairs`. This removes the 4M rank-scattered 4B
// global stores (R1: 4.7x write amplification, WRITE=76MB for 16MB).
// Rank overflow (>CAP per bucket per batch, ~0.4%) falls back to a direct
// scattered store at its exact reserved position.
__global__ __launch_bounds__(TPBC, 8)
void compute_scatter_kernel(const float* __restrict__ u1,
                            const int* __restrict__ edof,
                            const float* __restrict__ stiff,
                            const int* __restrict__ wgoff, // [nb][G1]
                            const int* __restrict__ bstart,
                            unsigned int* __restrict__ pairs,
                            int total, int nb, int chunk) {
    __shared__ unsigned int lstage[256 * CAP];   // 28 KB
    __shared__ int gstart[256];
    __shared__ int done[256];
    __shared__ int c[256];
    __shared__ int spos[257];
    int wg  = blockIdx.x;
    int tid = threadIdx.x;
    if (tid < nb) {
        gstart[tid] = bstart[tid] + wgoff[tid * G1 + wg];
        done[tid] = 0;
        c[tid] = 0;
    }
    __syncthreads();
    int k0 = wg * chunk;
    int k1 = min(k0 + chunk, total);
    for (int kb = k0; kb < k1; kb += BATCH) {
        // ---- accumulate phase: compute fe, stage into LDS ----
        for (int r = 0; r < RPT; ++r) {
            int k = kb + r * TPBC + tid;
            if (k < k1) {
                int e = k >> 3;
                int i = k & 7;
                int idx = __builtin_nontemporal_load(edof + k);
                float ue = u1[idx];

                const vfloat4* Kr = (const vfloat4*)(stiff + (size_t)e * 64 + (size_t)i * 8);
                vfloat4 ka = __builtin_nontemporal_load(Kr);
                vfloat4 kb4 = __builtin_nontemporal_load(Kr + 1);

                float fe;
                fe  = ka.x  * __shfl(ue, 0, 8);
                fe += ka.y  * __shfl(ue, 1, 8);
                fe += ka.z  * __shfl(ue, 2, 8);
                fe += ka.w  * __shfl(ue, 3, 8);
                fe += kb4.x * __shfl(ue, 4, 8);
                fe += kb4.y * __shfl(ue, 5, 8);
                fe += kb4.z * __shfl(ue, 6, 8);
                fe += kb4.w * __shfl(ue, 7, 8);

                unsigned short hu = __builtin_bit_cast(unsigned short, (_Float16)fe);
                unsigned int entry = ((unsigned)(idx & (BSIZE - 1)) << 16) | (unsigned)hu;
                int b  = idx >> BSHIFT;
                int rk = atomicAdd(&c[b], 1);
                if (rk < CAP) lstage[b * CAP + rk] = entry;
                else pairs[gstart[b] + done[b] + rk] = entry;   // rare overflow
            }
        }
        __syncthreads();
        // ---- scan phase: exclusive prefix over staged counts (wave 0) ----
        if (tid < 64) {
            int v[4];
            int s = 0;
            for (int j = 0; j < 4; ++j) {
                int b = tid * 4 + j;
                v[j] = (b < nb) ? min(c[b], CAP) : 0;
                s += v[j];
            }
            int incl = s;
            for (int off = 1; off < 64; off <<= 1) {
                int n = __shfl_up(incl, off, 64);
                if (tid >= off) incl += n;
            }
            int run = incl - s;
            for (int j = 0; j < 4; ++j) {
                spos[tid * 4 + j] = run;
                run += v[j];
            }
            if (tid == 63) spos[256] = incl;
        }
        __syncthreads();
        // ---- flush phase: coalesced copy LDS -> pairs ----
        int S = spos[nb];
        for (int t = tid; t < S; t += TPBC) {
            int lo = 0, hi = nb;          // find b: spos[b] <= t < spos[b+1]
            while (hi - lo > 1) {
                int mid = (lo + hi) >> 1;
                if (spos[mid] <= t) lo = mid; else hi = mid;
            }
            int b = lo;
            int r = t - spos[b];
            pairs[gstart[b] + done[b] + r] = lstage[b * CAP + r];
        }
        __syncthreads();
        if (tid < nb) { done[tid] += c[tid]; c[tid] = 0; }
        __syncthreads();
    }
}

// One workgroup per bucket. LDS fp32 accumulate, coalesced store.
// Covers every DOF, so no F memset needed.
__global__ void bucket_reduce_kernel(const unsigned int* __restrict__ pairs,
                                     const int* __restrict__ bstart,
                                     float* __restrict__ F, int ndof) {
    __shared__ float acc[BSIZE];
    int b = blockIdx.x;
    for (int j = threadIdx.x; j < BSIZE; j += 1024) acc[j] = 0.0f;
    __syncthreads();
    int k0 = bstart[b], k1 = bstart[b + 1];
    for (int k = k0 + threadIdx.x; k < k1; k += 1024) {
        unsigned p = pairs[k];
        float fe = (float)__builtin_bit_cast(_Float16, (unsigned short)(p & 0xffffu));
        atomicAdd(&acc[p >> 16], fe);
    }
    __syncthreads();
    int gbase = b << BSHIFT;
    for (int j = threadIdx.x; j < BSIZE; j += 1024) {
        int g = gbase + j;
        if (g < ndof) F[g] = acc[j];
    }
}

// Fallback (fused atomics) if ws too small.
__global__ void elem_assemble_kernel(const float* __restrict__ u1,
                                     const int* __restrict__ edof,
                                     const float* __restrict__ stiff,
                                     float* __restrict__ F, int nelem) {
    int t = blockIdx.x * blockDim.x + threadIdx.x;
    int e = t >> 3;
    if (e >= nelem) return;
    int i = t & 7;
    int idx = __builtin_nontemporal_load(edof + t);
    float ue = u1[idx];
    const vfloat4* Kr = (const vfloat4*)(stiff + (size_t)e * 64 + (size_t)i * 8);
    vfloat4 k0 = __builtin_nontemporal_load(Kr);
    vfloat4 k1 = __builtin_nontemporal_load(Kr + 1);
    float fe;
    fe  = k0.x * __shfl(ue, 0, 8);
    fe += k0.y * __shfl(ue, 1, 8);
    fe += k0.z * __shfl(ue, 2, 8);
    fe += k0.w * __shfl(ue, 3, 8);
    fe += k1.x * __shfl(ue, 4, 8);
    fe += k1.y * __shfl(ue, 5, 8);
    fe += k1.z * __shfl(ue, 6, 8);
    fe += k1.w * __shfl(ue, 7, 8);
    unsafeAtomicAdd(&F[idx], fe);
}

extern "C" void kernel_launch(void* const* d_in, const int* in_sizes, int n_in,
                              void* d_out, int out_size, void* d_ws, size_t ws_size,
                              hipStream_t stream) {
    const float* u     = (const float*)d_in[0];
    const float* w1    = (const float*)d_in[1];
    const int*   bc    = (const int*)d_in[2];
    const int*   edof  = (const int*)d_in[3];
    const float* stiff = (const float*)d_in[4];
    float* F = (float*)d_out;

    int ndof  = in_sizes[0];
    int nbc   = in_sizes[2];
    int total = in_sizes[3];      // NELEM * 8
    int nelem = total / 8;
    int nb    = (ndof + BSIZE - 1) >> BSHIFT;

    // Carve workspace (256 B aligned chunks).
    char* w = (char*)d_ws;
    size_t o = 0;
    auto take = [&](size_t nbytes) -> char* {
        char* p = w + o;
        o += (nbytes + 255) & ~(size_t)255;
        return p;
    };
    float* u1 = (float*)take((size_t)ndof * 4);
    unsigned int* pairs = (unsigned int*)take((size_t)total * 4);
    int* cnt    = (int*)take((size_t)nb * G1 * 4);
    int* wgoff  = (int*)take((size_t)nb * G1 * 4);
    int* btot   = (int*)take((size_t)nb * 4);
    int* bstart = (int*)take((size_t)(nb + 1) * 4);

    (void)hipMemsetAsync(u1, 0, (size_t)ndof * sizeof(float), stream);
    scatter_u1_kernel<<<(nbc + TPB - 1) / TPB, TPB, 0, stream>>>(u, w1, bc, u1, nbc);

    if (o <= ws_size && nb <= 256 && total % 8 == 0) {
        // chunk: multiple of BATCH (= also multiple of TPBC*4 for hist's vint4),
        // shared by both chunked kernels so cnt/wgoff line up.
        int chunk = (((total + G1 - 1) / G1) + BATCH - 1) & ~(BATCH - 1);
        hist_kernel<<<G1, TPBC, 0, stream>>>(edof, cnt, total, nb, chunk);
        scan_bucket_kernel<<<nb, 64, 0, stream>>>(cnt, wgoff, btot);
        scan_total_kernel<<<1, 64, 0, stream>>>(btot, bstart, nb);
        compute_scatter_kernel<<<G1, TPBC, 0, stream>>>(
            u1, edof, stiff, wgoff, bstart, pairs, total, nb, chunk);
        bucket_reduce_kernel<<<nb, 1024, 0, stream>>>(pairs, bstart, F, ndof);
    } else {
        (void)hipMemsetAsync(F, 0, (size_t)ndof * sizeof(float), stream);
        elem_assemble_kernel<<<(total + TPB - 1) / TPB, TPB, 0, stream>>>(
            u1, edof, stiff, F, nelem);
    }
}